// Round 2
// baseline (330.753 us; speedup 1.0000x reference)
//
#include <hip/hip_runtime.h>
#include <cstdint>
#include <cstddef>

typedef float  v4f __attribute__((ext_vector_type(4)));
typedef short  v8s __attribute__((ext_vector_type(8)));
typedef int    v4i __attribute__((ext_vector_type(4)));
typedef unsigned int v4u __attribute__((ext_vector_type(4)));

#define BB 8
#define NN 2048
#define DD 128
#define TI 16
#define NEGV (-9e15f)

__device__ __forceinline__ unsigned short f2bf(float x) {
  unsigned u = __float_as_uint(x);
  u = u + 0x7FFFu + ((u >> 16) & 1u);   // round-to-nearest-even
  return (unsigned short)(u >> 16);
}

// packed f32x2 -> bf16x2, RTNE (same rounding as f2bf), 1 VALU op instead of 6
__device__ __forceinline__ unsigned cvt_pk_bf16(float lo, float hi) {
  unsigned r;
  asm("v_cvt_pk_bf16_f32 %0, %1, %2" : "=v"(r) : "v"(lo), "v"(hi));
  return r;
}

// ---------------------------------------------------------------------------
// K1 (MFMA): Wh = h @ W, Wh1 = Wh·a[:128], Wh2 = Wh·a[128:], whbT = bf16(Wh)^T.
// Unchanged (correctness-verified).
// ---------------------------------------------------------------------------
__global__ __launch_bounds__(256) void gat_k1(
    const float* __restrict__ h, const float* __restrict__ W, const float* __restrict__ a,
    short* __restrict__ whbT, float* __restrict__ wh1g, float* __restrict__ wh2g)
{
  __shared__ __align__(16) unsigned short wT[DD * 136];
  __shared__ __align__(16) unsigned short staging[DD * 72];

  const int tid  = threadIdx.x;
  const int lane = tid & 63;
  const int wid  = tid >> 6;
  const int m16  = lane & 15;
  const int quad = lane >> 4;
  const int b    = blockIdx.y;
  const int i0   = blockIdx.x * 64;

  {
    const v4f* W4 = (const v4f*)W;
    #pragma unroll
    for (int it = 0; it < 16; it++) {
      int idx = it * 256 + tid;
      int k  = idx >> 5;
      int c4 = (idx & 31) * 4;
      v4f wv = W4[idx];
      #pragma unroll
      for (int q = 0; q < 4; q++)
        wT[(c4 + q) * 136 + k] = f2bf(wv[q]);
    }
  }

  const float* hrow = h + (size_t)(b * NN + i0 + wid * 16 + m16) * DD;
  v8s af[4];
  #pragma unroll
  for (int ks = 0; ks < 4; ks++) {
    v4f x0 = *(const v4f*)(hrow + ks * 32 + quad * 8);
    v4f x1 = *(const v4f*)(hrow + ks * 32 + quad * 8 + 4);
    v8s t;
    t[0] = (short)f2bf(x0.x); t[1] = (short)f2bf(x0.y);
    t[2] = (short)f2bf(x0.z); t[3] = (short)f2bf(x0.w);
    t[4] = (short)f2bf(x1.x); t[5] = (short)f2bf(x1.y);
    t[6] = (short)f2bf(x1.z); t[7] = (short)f2bf(x1.w);
    af[ks] = t;
  }
  __syncthreads();

  v4f acc[8];
  #pragma unroll
  for (int t = 0; t < 8; t++) acc[t] = (v4f){0.f, 0.f, 0.f, 0.f};

  #pragma unroll
  for (int ks = 0; ks < 4; ks++) {
    #pragma unroll
    for (int t = 0; t < 8; t++) {
      v8s bf = *(const v8s*)&wT[(t * 16 + m16) * 136 + ks * 32 + quad * 8];
      acc[t] = __builtin_amdgcn_mfma_f32_16x16x32_bf16(af[ks], bf, acc[t], 0, 0, 0);
    }
  }

  {
    float a1v[8], a2v[8];
    #pragma unroll
    for (int t = 0; t < 8; t++) {
      a1v[t] = a[t * 16 + m16];
      a2v[t] = a[DD + t * 16 + m16];
    }
    #pragma unroll
    for (int r = 0; r < 4; r++) {
      float p1 = 0.f, p2 = 0.f;
      #pragma unroll
      for (int t = 0; t < 8; t++) {
        p1 += acc[t][r] * a1v[t];
        p2 += acc[t][r] * a2v[t];
      }
      #pragma unroll
      for (int off = 8; off > 0; off >>= 1) {
        p1 += __shfl_xor(p1, off);
        p2 += __shfl_xor(p2, off);
      }
      if (m16 == 0) {
        int gi = b * NN + i0 + wid * 16 + quad * 4 + r;
        wh1g[gi] = p1;
        wh2g[gi] = p2;
      }
    }
  }

  #pragma unroll
  for (int t = 0; t < 8; t++)
    #pragma unroll
    for (int r = 0; r < 4; r++)
      staging[(t * 16 + m16) * 72 + wid * 16 + quad * 4 + r] = f2bf(acc[t][r]);
  __syncthreads();

  #pragma unroll
  for (int it = 0; it < 4; it++) {
    int idx = it * 256 + tid;
    int c  = idx >> 3;
    int i8 = idx & 7;
    v8s val = *(const v8s*)&staging[c * 72 + i8 * 8];
    *(v8s*)(whbT + (size_t)b * DD * NN + (size_t)c * NN + i0 + i8 * 8) = val;
  }
}

// ---------------------------------------------------------------------------
// K0: streaming adj pass (unchanged, correctness-verified). One wave per row.
// ---------------------------------------------------------------------------
__global__ __launch_bounds__(256) void gat_k0(
    const int* __restrict__ adj, const float* __restrict__ wh1g,
    const float* __restrict__ wh2g, unsigned* __restrict__ maskg,
    float* __restrict__ msg, float* __restrict__ rsg)
{
  const int tid  = threadIdx.x;
  const int lane = tid & 63;
  const int wid  = tid >> 6;
  const int b    = blockIdx.y;
  const int i    = blockIdx.x * 4 + wid;
  const size_t row = (size_t)b * NN + i;

  const v4i* arow = (const v4i*)(adj + row * NN);
  const v4f* w2   = (const v4f*)(wh2g + (size_t)b * NN);
  const float wh1v = wh1g[row];

  float e[32];
  float m = -INFINITY;
  unsigned mbits = 0u;
  #pragma unroll
  for (int u = 0; u < 8; u++) {
    v4i av  = __builtin_nontemporal_load(&arow[u * 64 + lane]);
    v4f w2v = w2[u * 64 + lane];
    #pragma unroll
    for (int q = 0; q < 4; q++) {
      bool mk = av[q] > 0;
      float x = wh1v + w2v[q];
      float ev = mk ? (x > 0.f ? x : 0.2f * x) : NEGV;
      e[u * 4 + q] = ev;
      m = fmaxf(m, ev);
      mbits |= (mk ? 1u : 0u) << (u * 4 + q);
    }
  }
  maskg[row * 64 + lane] = mbits;

  #pragma unroll
  for (int off = 32; off > 0; off >>= 1) m = fmaxf(m, __shfl_xor(m, off));
  float s = 0.f;
  #pragma unroll
  for (int k = 0; k < 32; k++) s += __expf(e[k] - m);
  #pragma unroll
  for (int off = 32; off > 0; off >>= 1) s += __shfl_xor(s, off);

  if (lane == 0) { msg[row] = m; rsg[row] = 1.f / s; }
}

// ---------------------------------------------------------------------------
// K2: barrier-free, with depth-1 whbT ping-pong so MFMA's vmcnt wait is
// COUNTED (loads issued before the phase's nt-stores -> stores never drained).
// ---------------------------------------------------------------------------
__global__ __launch_bounds__(256, 4) void gat_k2(
    const float* __restrict__ h, const unsigned* __restrict__ maskg,
    const short* __restrict__ whbT, const float* __restrict__ wh1g,
    const float* __restrict__ wh2g, const float* __restrict__ msg,
    const float* __restrict__ rsg, float* __restrict__ out,
    float* __restrict__ attout)
{
  __shared__ __align__(16) float smem[4 * TI * DD];   // 32KB: wh2s (main) / redbuf (epilogue)
  __shared__ unsigned masks[TI * 68];
  __shared__ float wh1s[TI], ms_s[TI], rs_s[TI];

  const int tid  = threadIdx.x;
  const int lane = tid & 63;
  const int wid  = tid >> 6;
  const int m16  = lane & 15;
  const int quad = lane >> 4;
  const int b    = blockIdx.y;
  const int i0   = blockIdx.x * TI;

  float* wh2s = smem;
  {
    const v4f* w2g4 = (const v4f*)(wh2g + (size_t)b * NN);
    ((v4f*)wh2s)[tid]       = w2g4[tid];
    ((v4f*)wh2s)[tid + 256] = w2g4[tid + 256];
  }
  {
    const unsigned* mg = maskg + (size_t)(b * NN + i0) * 64;
    #pragma unroll
    for (int it = 0; it < 4; it++) {
      int idx = it * 256 + tid;
      masks[(idx >> 6) * 68 + (idx & 63)] = mg[idx];
    }
  }
  if (tid < TI) {
    wh1s[tid] = wh1g[b * NN + i0 + tid];
    ms_s[tid] = msg[b * NN + i0 + tid];
    rs_s[tid] = rsg[b * NN + i0 + tid];
  }
  __syncthreads();

  const float wh1v = wh1s[m16];
  const float mi   = ms_s[m16];
  const float rsi  = rs_s[m16];
  const short* whbT_b = whbT + (size_t)b * DD * NN;
  float* attrow = attout + (size_t)(b * NN + i0 + m16) * NN;

  v4f acc[8];
  #pragma unroll
  for (int t = 0; t < 8; t++) acc[t] = (v4f){0.f, 0.f, 0.f, 0.f};

  v8s bfr0[8], bfr1[8];

  // phase p in [0,16): jb = wid*512 + (p>>1)*64 + (p&1)*32 + quad*8
  // prologue: load phase 0 into bfr0 (no stores outstanding yet)
  {
    const int jb0 = wid * 512 + quad * 8;
    #pragma unroll
    for (int t = 0; t < 8; t++)
      bfr0[t] = *(const v8s*)(whbT_b + (size_t)(t * 16 + m16) * NN + jb0);
  }

  auto phase = [&](int p, v8s (&cur)[8], v8s (&nxt)[8]) {
    const int jb  = wid * 512 + ((p >> 1) << 6) + ((p & 1) << 5) + quad * 8;
    const int pn  = (p + 1) & 15;          // p=15 wraps to a harmless re-load of phase 0
    const int jbn = wid * 512 + ((pn >> 1) << 6) + ((pn & 1) << 5) + quad * 8;

    // 1) issue next-phase whbT loads BEFORE this phase's stores.
    #pragma unroll
    for (int t = 0; t < 8; t++)
      nxt[t] = *(const v8s*)(whbT_b + (size_t)(t * 16 + m16) * NN + jbn);
    __builtin_amdgcn_sched_barrier(0);     // pin loads-before-stores order

    // 2) attention VALU for this phase
    const int ubit = (jb >> 8) << 2;       // bit = (j>>8)*4 + (j&3)
    v4f w2a = ((const v4f*)wh2s)[jb >> 2];
    v4f w2b = ((const v4f*)wh2s)[(jb >> 2) + 1];
    const int w0 = (jb >> 2) & 63;
    unsigned mwa = masks[m16 * 68 + w0];
    unsigned mwb = masks[m16 * 68 + w0 + 1];

    v4f at0, at1;
    #pragma unroll
    for (int q = 0; q < 4; q++) {
      float x = wh1v + w2a[q];
      float ev = ((mwa >> (ubit + q)) & 1u) ? (x > 0.f ? x : 0.2f * x) : NEGV;
      at0[q] = __expf(ev - mi) * rsi;
    }
    #pragma unroll
    for (int q = 0; q < 4; q++) {
      float x = wh1v + w2b[q];
      float ev = ((mwb >> (ubit + q)) & 1u) ? (x > 0.f ? x : 0.2f * x) : NEGV;
      at1[q] = __expf(ev - mi) * rsi;
    }
    union { v4u u; v8s s; } af;
    af.u[0] = cvt_pk_bf16(at0[0], at0[1]);
    af.u[1] = cvt_pk_bf16(at0[2], at0[3]);
    af.u[2] = cvt_pk_bf16(at1[0], at1[1]);
    af.u[3] = cvt_pk_bf16(at1[2], at1[3]);

    // 3) fp32 att stores (nontemporal, drain asynchronously)
    __builtin_nontemporal_store(at0, (v4f*)(attrow + jb));
    __builtin_nontemporal_store(at1, (v4f*)(attrow + jb + 4));

    // 4) MFMA from the buffer loaded LAST phase (older than any live store ->
    //    counted vmcnt, no store drain)
    #pragma unroll
    for (int t = 0; t < 8; t++)
      acc[t] = __builtin_amdgcn_mfma_f32_16x16x32_bf16(af.s, cur[t], acc[t], 0, 0, 0);
  };

  #pragma unroll 1
  for (int pc = 0; pc < 8; pc++) {
    phase(2 * pc,     bfr0, bfr1);
    phase(2 * pc + 1, bfr1, bfr0);
  }

  // ---- cross-wave reduction of h' partials
  __syncthreads();                       // wh2s dead; reuse smem
  float* red = smem;
  #pragma unroll
  for (int t = 0; t < 8; t++)
    #pragma unroll
    for (int r = 0; r < 4; r++)
      red[wid * (TI * DD) + (quad * 4 + r) * DD + t * 16 + m16] = acc[t][r];
  __syncthreads();

  {
    const size_t base = (size_t)(b * NN + i0) * DD;
    #pragma unroll
    for (int it = 0; it < 2; it++) {
      int idx = it * 256 + tid;
      v4f s0 = ((const v4f*)red)[idx];
      v4f s1 = ((const v4f*)red)[idx + 512];
      v4f s2 = ((const v4f*)red)[idx + 1024];
      v4f s3 = ((const v4f*)red)[idx + 1536];
      v4f hv = *(const v4f*)(h + base + (size_t)idx * 4);
      v4f o  = hv + s0 + s1 + s2 + s3;
      *(v4f*)(out + base + (size_t)idx * 4) = o;
    }
  }
}

extern "C" void kernel_launch(void* const* d_in, const int* in_sizes, int n_in,
                              void* d_out, int out_size, void* d_ws, size_t ws_size,
                              hipStream_t stream) {
  const float* h  = (const float*)d_in[0];
  const int* adj  = (const int*)d_in[1];
  const float* W  = (const float*)d_in[2];
  const float* a  = (const float*)d_in[3];

  float* out    = (float*)d_out;
  float* attout = out + (size_t)BB * NN * DD;

  char* ws = (char*)d_ws;
  short* whbT = (short*)ws;                      ws += (size_t)BB * DD * NN * 2;  // 8.39MB
  float* wh1  = (float*)ws;                      ws += (size_t)BB * NN * 4;
  float* wh2  = (float*)ws;                      ws += (size_t)BB * NN * 4;
  float* msg  = (float*)ws;                      ws += (size_t)BB * NN * 4;
  float* rsg  = (float*)ws;                      ws += (size_t)BB * NN * 4;
  unsigned* maskg = (unsigned*)ws;               // 4MB

  gat_k1<<<dim3(NN / 64, BB), 256, 0, stream>>>(h, W, a, whbT, wh1, wh2);
  gat_k0<<<dim3(NN / 4, BB), 256, 0, stream>>>(adj, wh1, wh2, maskg, msg, rsg);
  gat_k2<<<dim3(NN / TI, BB), 256, 0, stream>>>(h, maskg, whbT, wh1, wh2, msg, rsg, out, attout);
}

// Round 3
// 295.902 us; speedup vs baseline: 1.1178x; 1.1178x over previous
//
#include <hip/hip_runtime.h>
#include <cstdint>
#include <cstddef>

typedef float  v4f __attribute__((ext_vector_type(4)));
typedef short  v8s __attribute__((ext_vector_type(8)));
typedef int    v4i __attribute__((ext_vector_type(4)));
typedef unsigned long long u64;

#define BB 8
#define NN 2048
#define DD 128
#define TI 16
#define NEGV (-9e15f)

__device__ __forceinline__ unsigned short f2bf(float x) {
  unsigned u = __float_as_uint(x);
  u = u + 0x7FFFu + ((u >> 16) & 1u);   // round-to-nearest-even
  return (unsigned short)(u >> 16);
}

// packed f32x2 -> bf16x2, RTNE (same rounding as f2bf)
__device__ __forceinline__ unsigned cvt_pk_bf16(float lo, float hi) {
  unsigned r;
  asm("v_cvt_pk_bf16_f32 %0, %1, %2" : "=v"(r) : "v"(lo), "v"(hi));
  return r;
}

// ---------------------------------------------------------------------------
// K1 (MFMA): Wh = h @ W, Wh1 = Wh·a[:128], Wh2 = Wh·a[128:], whbT = bf16(Wh)^T.
// Unchanged (correctness-verified).
// ---------------------------------------------------------------------------
__global__ __launch_bounds__(256) void gat_k1(
    const float* __restrict__ h, const float* __restrict__ W, const float* __restrict__ a,
    short* __restrict__ whbT, float* __restrict__ wh1g, float* __restrict__ wh2g)
{
  __shared__ __align__(16) unsigned short wT[DD * 136];
  __shared__ __align__(16) unsigned short staging[DD * 72];

  const int tid  = threadIdx.x;
  const int lane = tid & 63;
  const int wid  = tid >> 6;
  const int m16  = lane & 15;
  const int quad = lane >> 4;
  const int b    = blockIdx.y;
  const int i0   = blockIdx.x * 64;

  {
    const v4f* W4 = (const v4f*)W;
    #pragma unroll
    for (int it = 0; it < 16; it++) {
      int idx = it * 256 + tid;
      int k  = idx >> 5;
      int c4 = (idx & 31) * 4;
      v4f wv = W4[idx];
      #pragma unroll
      for (int q = 0; q < 4; q++)
        wT[(c4 + q) * 136 + k] = f2bf(wv[q]);
    }
  }

  const float* hrow = h + (size_t)(b * NN + i0 + wid * 16 + m16) * DD;
  v8s af[4];
  #pragma unroll
  for (int ks = 0; ks < 4; ks++) {
    v4f x0 = *(const v4f*)(hrow + ks * 32 + quad * 8);
    v4f x1 = *(const v4f*)(hrow + ks * 32 + quad * 8 + 4);
    v8s t;
    t[0] = (short)f2bf(x0.x); t[1] = (short)f2bf(x0.y);
    t[2] = (short)f2bf(x0.z); t[3] = (short)f2bf(x0.w);
    t[4] = (short)f2bf(x1.x); t[5] = (short)f2bf(x1.y);
    t[6] = (short)f2bf(x1.z); t[7] = (short)f2bf(x1.w);
    af[ks] = t;
  }
  __syncthreads();

  v4f acc[8];
  #pragma unroll
  for (int t = 0; t < 8; t++) acc[t] = (v4f){0.f, 0.f, 0.f, 0.f};

  #pragma unroll
  for (int ks = 0; ks < 4; ks++) {
    #pragma unroll
    for (int t = 0; t < 8; t++) {
      v8s bf = *(const v8s*)&wT[(t * 16 + m16) * 136 + ks * 32 + quad * 8];
      acc[t] = __builtin_amdgcn_mfma_f32_16x16x32_bf16(af[ks], bf, acc[t], 0, 0, 0);
    }
  }

  {
    float a1v[8], a2v[8];
    #pragma unroll
    for (int t = 0; t < 8; t++) {
      a1v[t] = a[t * 16 + m16];
      a2v[t] = a[DD + t * 16 + m16];
    }
    #pragma unroll
    for (int r = 0; r < 4; r++) {
      float p1 = 0.f, p2 = 0.f;
      #pragma unroll
      for (int t = 0; t < 8; t++) {
        p1 += acc[t][r] * a1v[t];
        p2 += acc[t][r] * a2v[t];
      }
      #pragma unroll
      for (int off = 8; off > 0; off >>= 1) {
        p1 += __shfl_xor(p1, off);
        p2 += __shfl_xor(p2, off);
      }
      if (m16 == 0) {
        int gi = b * NN + i0 + wid * 16 + quad * 4 + r;
        wh1g[gi] = p1;
        wh2g[gi] = p2;
      }
    }
  }

  #pragma unroll
  for (int t = 0; t < 8; t++)
    #pragma unroll
    for (int r = 0; r < 4; r++)
      staging[(t * 16 + m16) * 72 + wid * 16 + quad * 4 + r] = f2bf(acc[t][r]);
  __syncthreads();

  #pragma unroll
  for (int it = 0; it < 4; it++) {
    int idx = it * 256 + tid;
    int c  = idx >> 3;
    int i8 = idx & 7;
    v8s val = *(const v8s*)&staging[c * 72 + i8 * 8];
    *(v8s*)(whbT + (size_t)b * DD * NN + (size_t)c * NN + i0 + i8 * 8) = val;
  }
}

// ---------------------------------------------------------------------------
// K0: streaming adj pass (unchanged, correctness-verified). One wave per row.
// ---------------------------------------------------------------------------
__global__ __launch_bounds__(256) void gat_k0(
    const int* __restrict__ adj, const float* __restrict__ wh1g,
    const float* __restrict__ wh2g, unsigned* __restrict__ maskg,
    float* __restrict__ msg, float* __restrict__ rsg)
{
  const int tid  = threadIdx.x;
  const int lane = tid & 63;
  const int wid  = tid >> 6;
  const int b    = blockIdx.y;
  const int i    = blockIdx.x * 4 + wid;
  const size_t row = (size_t)b * NN + i;

  const v4i* arow = (const v4i*)(adj + row * NN);
  const v4f* w2   = (const v4f*)(wh2g + (size_t)b * NN);
  const float wh1v = wh1g[row];

  float e[32];
  float m = -INFINITY;
  unsigned mbits = 0u;
  #pragma unroll
  for (int u = 0; u < 8; u++) {
    v4i av  = __builtin_nontemporal_load(&arow[u * 64 + lane]);
    v4f w2v = w2[u * 64 + lane];
    #pragma unroll
    for (int q = 0; q < 4; q++) {
      bool mk = av[q] > 0;
      float x = wh1v + w2v[q];
      float ev = mk ? (x > 0.f ? x : 0.2f * x) : NEGV;
      e[u * 4 + q] = ev;
      m = fmaxf(m, ev);
      mbits |= (mk ? 1u : 0u) << (u * 4 + q);
    }
  }
  maskg[row * 64 + lane] = mbits;

  #pragma unroll
  for (int off = 32; off > 0; off >>= 1) m = fmaxf(m, __shfl_xor(m, off));
  float s = 0.f;
  #pragma unroll
  for (int k = 0; k < 32; k++) s += __expf(e[k] - m);
  #pragma unroll
  for (int off = 32; off > 0; off >>= 1) s += __shfl_xor(s, off);

  if (lane == 0) { msg[row] = m; rsg[row] = 1.f / s; }
}

// ---------------------------------------------------------------------------
// K2 v3: barrier-free main loop; att computed in STORE layout (full-line HBM
// writes, no sector amplification); per-wave-private LDS tile relayouts att
// into MFMA A-fragment layout; XCD-aware block swizzle (b = bid & 7).
// ---------------------------------------------------------------------------
__global__ __launch_bounds__(256, 4) void gat_k2(
    const float* __restrict__ h, const unsigned* __restrict__ maskg,
    const short* __restrict__ whbT, const float* __restrict__ wh1g,
    const float* __restrict__ wh2g, const float* __restrict__ msg,
    const float* __restrict__ rsg, float* __restrict__ out,
    float* __restrict__ attout)
{
  // 32 KB block: [0,8K) wh2s, [8K,16.9K) per-wave atile; whole 32 KB = redbuf in epilogue
  __shared__ __align__(16) float smem[4 * TI * DD];
  __shared__ unsigned masks[TI * 68];
  __shared__ float wh1s[TI], ms_s[TI], rs_s[TI];

  const int tid  = threadIdx.x;
  const int lane = tid & 63;
  const int wid  = tid >> 6;
  const int m16  = lane & 15;
  const int quad = lane >> 4;
  const int bid  = blockIdx.x;
  const int b    = bid & 7;            // XCD swizzle: one batch per XCD
  const int i0   = (bid >> 3) * TI;

  float* wh2s = smem;
  unsigned short* atile = (unsigned short*)(smem + 2048) + wid * (TI * 68);

  {
    const v4f* w2g4 = (const v4f*)(wh2g + (size_t)b * NN);
    ((v4f*)wh2s)[tid]       = w2g4[tid];
    ((v4f*)wh2s)[tid + 256] = w2g4[tid + 256];
  }
  {
    const unsigned* mg = maskg + (size_t)(b * NN + i0) * 64;
    #pragma unroll
    for (int it = 0; it < 4; it++) {
      int idx = it * 256 + tid;
      masks[(idx >> 6) * 68 + (idx & 63)] = mg[idx];
    }
  }
  if (tid < TI) {
    wh1s[tid] = wh1g[b * NN + i0 + tid];
    ms_s[tid] = msg[b * NN + i0 + tid];
    rs_s[tid] = rsg[b * NN + i0 + tid];
  }
  __syncthreads();

  // per-lane row scalars for the 4 rows this lane computes (rows it*4+quad)
  float wh1r[4], mir[4], rsr[4];
  #pragma unroll
  for (int it = 0; it < 4; it++) {
    wh1r[it] = wh1s[it * 4 + quad];
    mir[it]  = ms_s[it * 4 + quad];
    rsr[it]  = rs_s[it * 4 + quad];
  }

  const short* whbT_b = whbT + (size_t)b * DD * NN;
  float* attbase = attout + (size_t)(b * NN + i0) * NN;

  v4f acc[8];
  #pragma unroll
  for (int t = 0; t < 8; t++) acc[t] = (v4f){0.f, 0.f, 0.f, 0.f};

  for (int c = 0; c < 8; c++) {
    const int j0 = wid * 512 + c * 64;
    const int jb = j0 + quad * 8;

    // 1) B-fragment loads FIRST (older than this chunk's stores -> MFMA's
    //    vmcnt wait never drains the store queue)
    v8s bfr0[8], bfr1[8];
    #pragma unroll
    for (int t = 0; t < 8; t++)
      bfr0[t] = *(const v8s*)(whbT_b + (size_t)(t * 16 + m16) * NN + jb);
    #pragma unroll
    for (int t = 0; t < 8; t++)
      bfr1[t] = *(const v8s*)(whbT_b + (size_t)(t * 16 + m16) * NN + jb + 32);

    // 2) attention in STORE layout: lane -> (row = it*4+quad, cols m16*4..+3).
    //    Each nt-store instruction writes 4 rows x 256B contiguous = full lines.
    const int ubit = (j0 >> 8) << 2;
    const int wq   = ((j0 >> 2) & 63) + m16;
    v4f w2v = ((const v4f*)wh2s)[(j0 >> 2) + m16];
    #pragma unroll
    for (int it = 0; it < 4; it++) {
      const int row = it * 4 + quad;
      unsigned mw = masks[row * 68 + wq];
      v4f at;
      #pragma unroll
      for (int q = 0; q < 4; q++) {
        float x = wh1r[it] + w2v[q];
        float ev = ((mw >> (ubit + q)) & 1u) ? (x > 0.f ? x : 0.2f * x) : NEGV;
        at[q] = __expf(ev - mir[it]) * rsr[it];
      }
      __builtin_nontemporal_store(at, (v4f*)(attbase + (size_t)row * NN + j0 + m16 * 4));
      // pack to bf16 into the wave-private LDS tile (row-major [16][68] shorts)
      unsigned lo = cvt_pk_bf16(at[0], at[1]);
      unsigned hi = cvt_pk_bf16(at[2], at[3]);
      u64 dv = (u64)lo | ((u64)hi << 32);
      *(u64*)&atile[row * 68 + m16 * 4] = dv;
    }

    // 3) A-fragments back from LDS in MFMA layout (row = m16, k = ks*32+quad*8)
    union { v8s s; u64 d[2]; } af0, af1;
    af0.d[0] = *(const u64*)&atile[m16 * 68 + quad * 8];
    af0.d[1] = *(const u64*)&atile[m16 * 68 + quad * 8 + 4];
    af1.d[0] = *(const u64*)&atile[m16 * 68 + 32 + quad * 8];
    af1.d[1] = *(const u64*)&atile[m16 * 68 + 32 + quad * 8 + 4];

    // 4) MFMA: 8 d-tiles x K=64
    #pragma unroll
    for (int t = 0; t < 8; t++)
      acc[t] = __builtin_amdgcn_mfma_f32_16x16x32_bf16(af0.s, bfr0[t], acc[t], 0, 0, 0);
    #pragma unroll
    for (int t = 0; t < 8; t++)
      acc[t] = __builtin_amdgcn_mfma_f32_16x16x32_bf16(af1.s, bfr1[t], acc[t], 0, 0, 0);
  }

  // ---- cross-wave reduction of h' partials (smem reused as 32 KB redbuf)
  __syncthreads();
  float* red = smem;
  #pragma unroll
  for (int t = 0; t < 8; t++)
    #pragma unroll
    for (int r = 0; r < 4; r++)
      red[wid * (TI * DD) + (quad * 4 + r) * DD + t * 16 + m16] = acc[t][r];
  __syncthreads();

  {
    const size_t base = (size_t)(b * NN + i0) * DD;
    #pragma unroll
    for (int it = 0; it < 2; it++) {
      int idx = it * 256 + tid;
      v4f s0 = ((const v4f*)red)[idx];
      v4f s1 = ((const v4f*)red)[idx + 512];
      v4f s2 = ((const v4f*)red)[idx + 1024];
      v4f s3 = ((const v4f*)red)[idx + 1536];
      v4f hv = *(const v4f*)(h + base + (size_t)idx * 4);
      v4f o  = hv + s0 + s1 + s2 + s3;
      *(v4f*)(out + base + (size_t)idx * 4) = o;
    }
  }
}

extern "C" void kernel_launch(void* const* d_in, const int* in_sizes, int n_in,
                              void* d_out, int out_size, void* d_ws, size_t ws_size,
                              hipStream_t stream) {
  const float* h  = (const float*)d_in[0];
  const int* adj  = (const int*)d_in[1];
  const float* W  = (const float*)d_in[2];
  const float* a  = (const float*)d_in[3];

  float* out    = (float*)d_out;
  float* attout = out + (size_t)BB * NN * DD;

  char* ws = (char*)d_ws;
  short* whbT = (short*)ws;                      ws += (size_t)BB * DD * NN * 2;  // 8.39MB
  float* wh1  = (float*)ws;                      ws += (size_t)BB * NN * 4;
  float* wh2  = (float*)ws;                      ws += (size_t)BB * NN * 4;
  float* msg  = (float*)ws;                      ws += (size_t)BB * NN * 4;
  float* rsg  = (float*)ws;                      ws += (size_t)BB * NN * 4;
  unsigned* maskg = (unsigned*)ws;               // 4MB

  gat_k1<<<dim3(NN / 64, BB), 256, 0, stream>>>(h, W, a, whbT, wh1, wh2);
  gat_k0<<<dim3(NN / 4, BB), 256, 0, stream>>>(adj, wh1, wh2, maskg, msg, rsg);
  gat_k2<<<dim3(NN / TI * BB), 256, 0, stream>>>(h, maskg, whbT, wh1, wh2, msg, rsg, out, attout);
}

// Round 4
// 289.142 us; speedup vs baseline: 1.1439x; 1.0234x over previous
//
#include <hip/hip_runtime.h>
#include <cstdint>
#include <cstddef>

typedef float  v4f __attribute__((ext_vector_type(4)));
typedef short  v8s __attribute__((ext_vector_type(8)));
typedef int    v4i __attribute__((ext_vector_type(4)));
typedef unsigned long long u64;

#define BB 8
#define NN 2048
#define DD 128
#define TI 16
#define NEGV (-9e15f)

__device__ __forceinline__ unsigned short f2bf(float x) {
  unsigned u = __float_as_uint(x);
  u = u + 0x7FFFu + ((u >> 16) & 1u);   // round-to-nearest-even
  return (unsigned short)(u >> 16);
}

// packed f32x2 -> bf16x2, RTNE (same rounding as f2bf)
__device__ __forceinline__ unsigned cvt_pk_bf16(float lo, float hi) {
  unsigned r;
  asm("v_cvt_pk_bf16_f32 %0, %1, %2" : "=v"(r) : "v"(lo), "v"(hi));
  return r;
}

// ---------------------------------------------------------------------------
// K1 (MFMA): Wh = h @ W, Wh1 = Wh·a[:128], Wh2 = Wh·a[128:], whbT = bf16(Wh)^T.
// Unchanged (correctness-verified).
// ---------------------------------------------------------------------------
__global__ __launch_bounds__(256) void gat_k1(
    const float* __restrict__ h, const float* __restrict__ W, const float* __restrict__ a,
    short* __restrict__ whbT, float* __restrict__ wh1g, float* __restrict__ wh2g)
{
  __shared__ __align__(16) unsigned short wT[DD * 136];
  __shared__ __align__(16) unsigned short staging[DD * 72];

  const int tid  = threadIdx.x;
  const int lane = tid & 63;
  const int wid  = tid >> 6;
  const int m16  = lane & 15;
  const int quad = lane >> 4;
  const int b    = blockIdx.y;
  const int i0   = blockIdx.x * 64;

  {
    const v4f* W4 = (const v4f*)W;
    #pragma unroll
    for (int it = 0; it < 16; it++) {
      int idx = it * 256 + tid;
      int k  = idx >> 5;
      int c4 = (idx & 31) * 4;
      v4f wv = W4[idx];
      #pragma unroll
      for (int q = 0; q < 4; q++)
        wT[(c4 + q) * 136 + k] = f2bf(wv[q]);
    }
  }

  const float* hrow = h + (size_t)(b * NN + i0 + wid * 16 + m16) * DD;
  v8s af[4];
  #pragma unroll
  for (int ks = 0; ks < 4; ks++) {
    v4f x0 = *(const v4f*)(hrow + ks * 32 + quad * 8);
    v4f x1 = *(const v4f*)(hrow + ks * 32 + quad * 8 + 4);
    v8s t;
    t[0] = (short)f2bf(x0.x); t[1] = (short)f2bf(x0.y);
    t[2] = (short)f2bf(x0.z); t[3] = (short)f2bf(x0.w);
    t[4] = (short)f2bf(x1.x); t[5] = (short)f2bf(x1.y);
    t[6] = (short)f2bf(x1.z); t[7] = (short)f2bf(x1.w);
    af[ks] = t;
  }
  __syncthreads();

  v4f acc[8];
  #pragma unroll
  for (int t = 0; t < 8; t++) acc[t] = (v4f){0.f, 0.f, 0.f, 0.f};

  #pragma unroll
  for (int ks = 0; ks < 4; ks++) {
    #pragma unroll
    for (int t = 0; t < 8; t++) {
      v8s bf = *(const v8s*)&wT[(t * 16 + m16) * 136 + ks * 32 + quad * 8];
      acc[t] = __builtin_amdgcn_mfma_f32_16x16x32_bf16(af[ks], bf, acc[t], 0, 0, 0);
    }
  }

  {
    float a1v[8], a2v[8];
    #pragma unroll
    for (int t = 0; t < 8; t++) {
      a1v[t] = a[t * 16 + m16];
      a2v[t] = a[DD + t * 16 + m16];
    }
    #pragma unroll
    for (int r = 0; r < 4; r++) {
      float p1 = 0.f, p2 = 0.f;
      #pragma unroll
      for (int t = 0; t < 8; t++) {
        p1 += acc[t][r] * a1v[t];
        p2 += acc[t][r] * a2v[t];
      }
      #pragma unroll
      for (int off = 8; off > 0; off >>= 1) {
        p1 += __shfl_xor(p1, off);
        p2 += __shfl_xor(p2, off);
      }
      if (m16 == 0) {
        int gi = b * NN + i0 + wid * 16 + quad * 4 + r;
        wh1g[gi] = p1;
        wh2g[gi] = p2;
      }
    }
  }

  #pragma unroll
  for (int t = 0; t < 8; t++)
    #pragma unroll
    for (int r = 0; r < 4; r++)
      staging[(t * 16 + m16) * 72 + wid * 16 + quad * 4 + r] = f2bf(acc[t][r]);
  __syncthreads();

  #pragma unroll
  for (int it = 0; it < 4; it++) {
    int idx = it * 256 + tid;
    int c  = idx >> 3;
    int i8 = idx & 7;
    v8s val = *(const v8s*)&staging[c * 72 + i8 * 8];
    *(v8s*)(whbT + (size_t)b * DD * NN + (size_t)c * NN + i0 + i8 * 8) = val;
  }
}

// ---------------------------------------------------------------------------
// K0: streaming adj pass (unchanged, correctness-verified). One wave per row.
// ---------------------------------------------------------------------------
__global__ __launch_bounds__(256) void gat_k0(
    const int* __restrict__ adj, const float* __restrict__ wh1g,
    const float* __restrict__ wh2g, unsigned* __restrict__ maskg,
    float* __restrict__ msg, float* __restrict__ rsg)
{
  const int tid  = threadIdx.x;
  const int lane = tid & 63;
  const int wid  = tid >> 6;
  const int b    = blockIdx.y;
  const int i    = blockIdx.x * 4 + wid;
  const size_t row = (size_t)b * NN + i;

  const v4i* arow = (const v4i*)(adj + row * NN);
  const v4f* w2   = (const v4f*)(wh2g + (size_t)b * NN);
  const float wh1v = wh1g[row];

  float e[32];
  float m = -INFINITY;
  unsigned mbits = 0u;
  #pragma unroll
  for (int u = 0; u < 8; u++) {
    v4i av  = __builtin_nontemporal_load(&arow[u * 64 + lane]);
    v4f w2v = w2[u * 64 + lane];
    #pragma unroll
    for (int q = 0; q < 4; q++) {
      bool mk = av[q] > 0;
      float x = wh1v + w2v[q];
      float ev = mk ? (x > 0.f ? x : 0.2f * x) : NEGV;
      e[u * 4 + q] = ev;
      m = fmaxf(m, ev);
      mbits |= (mk ? 1u : 0u) << (u * 4 + q);
    }
  }
  maskg[row * 64 + lane] = mbits;

  #pragma unroll
  for (int off = 32; off > 0; off >>= 1) m = fmaxf(m, __shfl_xor(m, off));
  float s = 0.f;
  #pragma unroll
  for (int k = 0; k < 32; k++) s += __expf(e[k] - m);
  #pragma unroll
  for (int off = 32; off > 0; off >>= 1) s += __shfl_xor(s, off);

  if (lane == 0) { msg[row] = m; rsg[row] = 1.f / s; }
}

// ---------------------------------------------------------------------------
// K2 v4: identical to v3 except att stores are PLAIN (not nontemporal).
// Theory: the nt write-around path caps the 134MB att stream at ~1.7 TB/s
// (every nt-heavy kernel measured 1.7-2.5 TB/s; the plain-store fill kernel
// sustains 6.6 TB/s). Plain stores land in L2/L3 at cache BW and drain async.
// ---------------------------------------------------------------------------
__global__ __launch_bounds__(256, 4) void gat_k2(
    const float* __restrict__ h, const unsigned* __restrict__ maskg,
    const short* __restrict__ whbT, const float* __restrict__ wh1g,
    const float* __restrict__ wh2g, const float* __restrict__ msg,
    const float* __restrict__ rsg, float* __restrict__ out,
    float* __restrict__ attout)
{
  // 32 KB block: [0,8K) wh2s, [8K,16.9K) per-wave atile; whole 32 KB = redbuf in epilogue
  __shared__ __align__(16) float smem[4 * TI * DD];
  __shared__ unsigned masks[TI * 68];
  __shared__ float wh1s[TI], ms_s[TI], rs_s[TI];

  const int tid  = threadIdx.x;
  const int lane = tid & 63;
  const int wid  = tid >> 6;
  const int m16  = lane & 15;
  const int quad = lane >> 4;
  const int bid  = blockIdx.x;
  const int b    = bid & 7;            // XCD swizzle: one batch per XCD
  const int i0   = (bid >> 3) * TI;

  float* wh2s = smem;
  unsigned short* atile = (unsigned short*)(smem + 2048) + wid * (TI * 68);

  {
    const v4f* w2g4 = (const v4f*)(wh2g + (size_t)b * NN);
    ((v4f*)wh2s)[tid]       = w2g4[tid];
    ((v4f*)wh2s)[tid + 256] = w2g4[tid + 256];
  }
  {
    const unsigned* mg = maskg + (size_t)(b * NN + i0) * 64;
    #pragma unroll
    for (int it = 0; it < 4; it++) {
      int idx = it * 256 + tid;
      masks[(idx >> 6) * 68 + (idx & 63)] = mg[idx];
    }
  }
  if (tid < TI) {
    wh1s[tid] = wh1g[b * NN + i0 + tid];
    ms_s[tid] = msg[b * NN + i0 + tid];
    rs_s[tid] = rsg[b * NN + i0 + tid];
  }
  __syncthreads();

  // per-lane row scalars for the 4 rows this lane computes (rows it*4+quad)
  float wh1r[4], mir[4], rsr[4];
  #pragma unroll
  for (int it = 0; it < 4; it++) {
    wh1r[it] = wh1s[it * 4 + quad];
    mir[it]  = ms_s[it * 4 + quad];
    rsr[it]  = rs_s[it * 4 + quad];
  }

  const short* whbT_b = whbT + (size_t)b * DD * NN;
  float* attbase = attout + (size_t)(b * NN + i0) * NN;

  v4f acc[8];
  #pragma unroll
  for (int t = 0; t < 8; t++) acc[t] = (v4f){0.f, 0.f, 0.f, 0.f};

  for (int c = 0; c < 8; c++) {
    const int j0 = wid * 512 + c * 64;
    const int jb = j0 + quad * 8;

    // 1) B-fragment loads FIRST (older than this chunk's stores -> MFMA's
    //    vmcnt wait never drains the store queue)
    v8s bfr0[8], bfr1[8];
    #pragma unroll
    for (int t = 0; t < 8; t++)
      bfr0[t] = *(const v8s*)(whbT_b + (size_t)(t * 16 + m16) * NN + jb);
    #pragma unroll
    for (int t = 0; t < 8; t++)
      bfr1[t] = *(const v8s*)(whbT_b + (size_t)(t * 16 + m16) * NN + jb + 32);

    // 2) attention in STORE layout: lane -> (row = it*4+quad, cols m16*4..+3).
    //    Each store instruction writes 4 rows x 256B contiguous = full lines.
    const int ubit = (j0 >> 8) << 2;
    const int wq   = ((j0 >> 2) & 63) + m16;
    v4f w2v = ((const v4f*)wh2s)[(j0 >> 2) + m16];
    #pragma unroll
    for (int it = 0; it < 4; it++) {
      const int row = it * 4 + quad;
      unsigned mw = masks[row * 68 + wq];
      v4f at;
      #pragma unroll
      for (int q = 0; q < 4; q++) {
        float x = wh1r[it] + w2v[q];
        float ev = ((mw >> (ubit + q)) & 1u) ? (x > 0.f ? x : 0.2f * x) : NEGV;
        at[q] = __expf(ev - mir[it]) * rsr[it];
      }
      *(v4f*)(attbase + (size_t)row * NN + j0 + m16 * 4) = at;   // PLAIN store
      // pack to bf16 into the wave-private LDS tile (row-major [16][68] shorts)
      unsigned lo = cvt_pk_bf16(at[0], at[1]);
      unsigned hi = cvt_pk_bf16(at[2], at[3]);
      u64 dv = (u64)lo | ((u64)hi << 32);
      *(u64*)&atile[row * 68 + m16 * 4] = dv;
    }

    // 3) A-fragments back from LDS in MFMA layout (row = m16, k = ks*32+quad*8)
    union { v8s s; u64 d[2]; } af0, af1;
    af0.d[0] = *(const u64*)&atile[m16 * 68 + quad * 8];
    af0.d[1] = *(const u64*)&atile[m16 * 68 + quad * 8 + 4];
    af1.d[0] = *(const u64*)&atile[m16 * 68 + 32 + quad * 8];
    af1.d[1] = *(const u64*)&atile[m16 * 68 + 32 + quad * 8 + 4];

    // 4) MFMA: 8 d-tiles x K=64
    #pragma unroll
    for (int t = 0; t < 8; t++)
      acc[t] = __builtin_amdgcn_mfma_f32_16x16x32_bf16(af0.s, bfr0[t], acc[t], 0, 0, 0);
    #pragma unroll
    for (int t = 0; t < 8; t++)
      acc[t] = __builtin_amdgcn_mfma_f32_16x16x32_bf16(af1.s, bfr1[t], acc[t], 0, 0, 0);
  }

  // ---- cross-wave reduction of h' partials (smem reused as 32 KB redbuf)
  __syncthreads();
  float* red = smem;
  #pragma unroll
  for (int t = 0; t < 8; t++)
    #pragma unroll
    for (int r = 0; r < 4; r++)
      red[wid * (TI * DD) + (quad * 4 + r) * DD + t * 16 + m16] = acc[t][r];
  __syncthreads();

  {
    const size_t base = (size_t)(b * NN + i0) * DD;
    #pragma unroll
    for (int it = 0; it < 2; it++) {
      int idx = it * 256 + tid;
      v4f s0 = ((const v4f*)red)[idx];
      v4f s1 = ((const v4f*)red)[idx + 512];
      v4f s2 = ((const v4f*)red)[idx + 1024];
      v4f s3 = ((const v4f*)red)[idx + 1536];
      v4f hv = *(const v4f*)(h + base + (size_t)idx * 4);
      v4f o  = hv + s0 + s1 + s2 + s3;
      *(v4f*)(out + base + (size_t)idx * 4) = o;
    }
  }
}

extern "C" void kernel_launch(void* const* d_in, const int* in_sizes, int n_in,
                              void* d_out, int out_size, void* d_ws, size_t ws_size,
                              hipStream_t stream) {
  const float* h  = (const float*)d_in[0];
  const int* adj  = (const int*)d_in[1];
  const float* W  = (const float*)d_in[2];
  const float* a  = (const float*)d_in[3];

  float* out    = (float*)d_out;
  float* attout = out + (size_t)BB * NN * DD;

  char* ws = (char*)d_ws;
  short* whbT = (short*)ws;                      ws += (size_t)BB * DD * NN * 2;  // 8.39MB
  float* wh1  = (float*)ws;                      ws += (size_t)BB * NN * 4;
  float* wh2  = (float*)ws;                      ws += (size_t)BB * NN * 4;
  float* msg  = (float*)ws;                      ws += (size_t)BB * NN * 4;
  float* rsg  = (float*)ws;                      ws += (size_t)BB * NN * 4;
  unsigned* maskg = (unsigned*)ws;               // 4MB

  gat_k1<<<dim3(NN / 64, BB), 256, 0, stream>>>(h, W, a, whbT, wh1, wh2);
  gat_k0<<<dim3(NN / 4, BB), 256, 0, stream>>>(adj, wh1, wh2, maskg, msg, rsg);
  gat_k2<<<dim3(NN / TI * BB), 256, 0, stream>>>(h, maskg, whbT, wh1, wh2, msg, rsg, out, attout);
}